// Round 7
// baseline (60.062 us; speedup 1.0000x reference)
//
#include <hip/hip_runtime.h>

// Problem constants (from reference): B=8, N=65536, P=12, G=64
#define BB 8
#define NN 65536
#define PP 12
#define GG 64
#define G3 (GG*GG*GG)
#define NBLOCKS 2048   // (B*N)/256

// Last-block-done counter. Module-scope __device__ globals are zero-initialized
// at .so load (NOT part of d_ws, so never poisoned). The finalizer resets it to
// 0 every call, so every kernel_launch performs identical work -> deterministic.
__device__ unsigned long long g_counter = 0;

// Contribution of reflecting point (px,py,pz) across raw plane pl.
// Matches reference math: normalize plane in f32, reflect, idx3 = ceil((r+0.5)*G-0.5),
// combine in int32 (wraps identically), clip combined index, mask = 1 - voxel.
// When voxel[idx]==1 the reference zeroes the contribution, so the cp gather
// (3 dwords) and distance math are predicated off (~30% fewer L2 requests).
__device__ __forceinline__ float plane_contrib(
    float px, float py, float pz, float4 pl,
    const float* __restrict__ cpb, const float* __restrict__ voxb)
{
    float nx = pl.x, ny = pl.y, nz = pl.z, d = pl.w;
    float norm = sqrtf(nx * nx + ny * ny + nz * nz);
    float inv = 1.0f / norm;
    nx *= inv; ny *= inv; nz *= inv; d *= inv;

    float t = 2.0f * (px * nx + py * ny + pz * nz + d);
    float rx = px - t * nx;
    float ry = py - t * ny;
    float rz = pz - t * nz;

    int ix = (int)ceilf((rx + 0.5f) * 64.0f - 0.5f);
    int iy = (int)ceilf((ry + 0.5f) * 64.0f - 0.5f);
    int iz = (int)ceilf((rz + 0.5f) * 64.0f - 0.5f);
    int idx = ix * 4096 + iy * 64 + iz;
    idx = min(max(idx, 0), G3 - 1);

    float contrib = 0.0f;
    // voxel values are exactly 0.0f or 1.0f; occupied -> contribution is 0.
    if (voxb[idx] == 0.0f) {
        const float* cp = cpb + (size_t)idx * 3;
        float dx = rx - cp[0];
        float dy = ry - cp[1];
        float dz = rz - cp[2];
        contrib = dx * dx + dy * dy + dz * dz;
    }
    return contrib;
}

__global__ __launch_bounds__(256) void sym_plane_fused_kernel(
    const float* __restrict__ voxel,     // (B, G,G,G)
    const float* __restrict__ points,    // (B, N, 3)
    const float* __restrict__ closest,   // (B, G^3, 3)
    const float* __restrict__ planes,    // (B, P, 4)
    float* __restrict__ partial,         // (NBLOCKS,) in d_ws
    float* __restrict__ out)             // scalar
{
    // XCD-aware mapping: blocks round-robin over the 8 XCDs, so batch =
    // blockIdx&7 keeps each batch's 4MB of gather tables in ONE XCD's 4MB L2.
    int b = blockIdx.x & 7;
    int i = (blockIdx.x >> 3) * 256 + threadIdx.x;   // 0 .. N-1

    const float* pt = points + ((size_t)b * NN + (size_t)i) * 3;
    // Nontemporal: points are streamed once; don't evict the gather tables.
    float px = __builtin_nontemporal_load(pt + 0);
    float py = __builtin_nontemporal_load(pt + 1);
    float pz = __builtin_nontemporal_load(pt + 2);

    // Flat positions f in [12*i, 12*i+12) all map to point i; plane q = f >> 16.
    int f0 = i * 12;
    int q0 = f0 >> 16;
    int q1 = (f0 + 11) >> 16;

    const float* cpb  = closest + (size_t)b * G3 * 3;
    const float* voxb = voxel   + (size_t)b * G3;
    const float4* plb = (const float4*)planes + (size_t)b * PP;

    float sum;
    if (q0 == q1) {
        sum = 12.0f * plane_contrib(px, py, pz, plb[q0], cpb, voxb);
    } else {
        int c0 = (q1 << 16) - f0;     // positions using plane q0 (11 threads/batch)
        sum = (float)c0        * plane_contrib(px, py, pz, plb[q0], cpb, voxb)
            + (float)(12 - c0) * plane_contrib(px, py, pz, plb[q1], cpb, voxb);
    }

    // Block reduction: wave64 shuffle, then LDS across 4 waves.
    for (int off = 32; off > 0; off >>= 1)
        sum += __shfl_down(sum, off, 64);

    __shared__ float wsum[4];
    __shared__ int slast;
    int lane = threadIdx.x & 63;
    int wid  = threadIdx.x >> 6;
    if (lane == 0) wsum[wid] = sum;
    __syncthreads();

    if (threadIdx.x == 0) {
        float bsum = wsum[0] + wsum[1] + wsum[2] + wsum[3];
        // Publish partial (agent-scope release: visible past this XCD's L2),
        // then join the RMW chain. The block seeing old==NBLOCKS-1 is last:
        // all partials are release-published before its acquire.
        __hip_atomic_store(partial + blockIdx.x, bsum,
                           __ATOMIC_RELEASE, __HIP_MEMORY_SCOPE_AGENT);
        unsigned long long old = __hip_atomic_fetch_add(
            &g_counter, 1ULL, __ATOMIC_ACQ_REL, __HIP_MEMORY_SCOPE_AGENT);
        slast = (old == (unsigned long long)(NBLOCKS - 1));
        if (slast)
            __hip_atomic_store(&g_counter, 0ULL,
                               __ATOMIC_RELAXED, __HIP_MEMORY_SCOPE_AGENT);  // ready for next call
    }
    __syncthreads();

    if (slast) {
        float s = 0.0f;
        #pragma unroll
        for (int j = 0; j < NBLOCKS / 256; ++j)
            s += __hip_atomic_load(partial + j * 256 + (int)threadIdx.x,
                                   __ATOMIC_RELAXED, __HIP_MEMORY_SCOPE_AGENT);

        for (int off = 32; off > 0; off >>= 1)
            s += __shfl_down(s, off, 64);

        __syncthreads();                 // wsum reads above are done; safe to reuse
        if (lane == 0) wsum[wid] = s;
        __syncthreads();
        if (threadIdx.x == 0)
            out[0] = (wsum[0] + wsum[1] + wsum[2] + wsum[3]) * (1.0f / (float)(BB * PP));
    }
}

extern "C" void kernel_launch(void* const* d_in, const int* in_sizes, int n_in,
                              void* d_out, int out_size, void* d_ws, size_t ws_size,
                              hipStream_t stream) {
    const float* voxel   = (const float*)d_in[0];
    const float* points  = (const float*)d_in[1];
    const float* closest = (const float*)d_in[2];
    const float* planes  = (const float*)d_in[3];
    float* out     = (float*)d_out;
    float* partial = (float*)d_ws;       // NBLOCKS floats, rewritten every call

    hipLaunchKernelGGL(sym_plane_fused_kernel, dim3(NBLOCKS), dim3(256), 0, stream,
                       voxel, points, closest, planes, partial, out);
}

// Round 8
// 13.525 us; speedup vs baseline: 4.4409x; 4.4409x over previous
//
#include <hip/hip_runtime.h>

// Problem constants (from reference): B=8, N=65536, P=12, G=64
#define BB 8
#define NN 65536
#define PP 12
#define GG 64
#define G3 (GG*GG*GG)
#define NBLOCKS 2048   // (B*N)/256
#define SLOTS 64       // sharded accumulator/counter slots (32 blocks each)
#define SPAD 16        // 16 dwords = 64B: one cache line per slot

// Module-scope state: zero-initialized at .so load, and every call returns all
// of it to exactly zero (slot-terminal blocks reset counters, finalizer resets
// accumulators) -> every kernel_launch does identical work, no cross-call state.
// NOT in d_ws, so never poisoned by the harness.
__device__ float    g_acc[SLOTS * SPAD];   // per-slot partial sums (atomic f32 add)
__device__ unsigned g_cnt[SLOTS * SPAD];   // per-slot arrival counters (0..32)
__device__ unsigned g_l2[SPAD];            // second-level counter (0..64)

// Contribution of reflecting point (px,py,pz) across raw plane pl.
// Matches reference math: normalize plane in f32, reflect, idx3 = ceil((r+0.5)*G-0.5),
// combine in int32 (wraps identically), clip combined index, mask = 1 - voxel.
// voxel==1 -> contribution is exactly 0, so cp gather + math are predicated off.
__device__ __forceinline__ float plane_contrib(
    float px, float py, float pz, float4 pl,
    const float* __restrict__ cpb, const float* __restrict__ voxb)
{
    float nx = pl.x, ny = pl.y, nz = pl.z, d = pl.w;
    float norm = sqrtf(nx * nx + ny * ny + nz * nz);
    float inv = 1.0f / norm;
    nx *= inv; ny *= inv; nz *= inv; d *= inv;

    float t = 2.0f * (px * nx + py * ny + pz * nz + d);
    float rx = px - t * nx;
    float ry = py - t * ny;
    float rz = pz - t * nz;

    int ix = (int)ceilf((rx + 0.5f) * 64.0f - 0.5f);
    int iy = (int)ceilf((ry + 0.5f) * 64.0f - 0.5f);
    int iz = (int)ceilf((rz + 0.5f) * 64.0f - 0.5f);
    int idx = ix * 4096 + iy * 64 + iz;
    idx = min(max(idx, 0), G3 - 1);

    float contrib = 0.0f;
    if (voxb[idx] == 0.0f) {
        const float* cp = cpb + (size_t)idx * 3;
        float dx = rx - cp[0];
        float dy = ry - cp[1];
        float dz = rz - cp[2];
        contrib = dx * dx + dy * dy + dz * dz;
    }
    return contrib;
}

__global__ __launch_bounds__(256) void sym_plane_fused_kernel(
    const float* __restrict__ voxel,     // (B, G,G,G)
    const float* __restrict__ points,    // (B, N, 3)
    const float* __restrict__ closest,   // (B, G^3, 3)
    const float* __restrict__ planes,    // (B, P, 4)
    float* __restrict__ out)             // scalar
{
    // XCD-aware mapping: blocks round-robin over the 8 XCDs, so batch =
    // blockIdx&7 keeps each batch's 4MB of gather tables in ONE XCD's 4MB L2.
    int b = blockIdx.x & 7;
    int i = (blockIdx.x >> 3) * 256 + threadIdx.x;   // 0 .. N-1

    const float* pt = points + ((size_t)b * NN + (size_t)i) * 3;
    float px = __builtin_nontemporal_load(pt + 0);
    float py = __builtin_nontemporal_load(pt + 1);
    float pz = __builtin_nontemporal_load(pt + 2);

    // Flat positions f in [12*i, 12*i+12) all map to point i; plane q = f >> 16.
    int f0 = i * 12;
    int q0 = f0 >> 16;
    int q1 = (f0 + 11) >> 16;

    const float* cpb  = closest + (size_t)b * G3 * 3;
    const float* voxb = voxel   + (size_t)b * G3;
    const float4* plb = (const float4*)planes + (size_t)b * PP;

    float sum;
    if (q0 == q1) {
        sum = 12.0f * plane_contrib(px, py, pz, plb[q0], cpb, voxb);
    } else {
        int c0 = (q1 << 16) - f0;
        sum = (float)c0        * plane_contrib(px, py, pz, plb[q0], cpb, voxb)
            + (float)(12 - c0) * plane_contrib(px, py, pz, plb[q1], cpb, voxb);
    }

    // Block reduction: wave64 shuffle, then LDS across 4 waves.
    for (int off = 32; off > 0; off >>= 1)
        sum += __shfl_down(sum, off, 64);

    __shared__ float wsum[4];
    __shared__ int sfin;
    int lane = threadIdx.x & 63;
    int wid  = threadIdx.x >> 6;
    if (lane == 0) wsum[wid] = sum;
    __syncthreads();

    if (threadIdx.x == 0) {
        float bsum = wsum[0] + wsum[1] + wsum[2] + wsum[3];
        int slot = (int)blockIdx.x & (SLOTS - 1);

        // RELAXED memory-side RMWs only (no release/acquire -> no per-block L2
        // writeback/invalidate, the R7 killer). Ordering via ack chain: each
        // returning RMW is drained with vmcnt(0) before the next issues, so
        // value-add is globally complete before the count-add lands.
        float oacc = __hip_atomic_fetch_add(&g_acc[slot * SPAD], bsum,
                                            __ATOMIC_RELAXED, __HIP_MEMORY_SCOPE_AGENT);
        asm volatile("" :: "v"(oacc));                  // force returning form
        asm volatile("s_waitcnt vmcnt(0)" ::: "memory");

        sfin = 0;
        unsigned oc = __hip_atomic_fetch_add(&g_cnt[slot * SPAD], 1u,
                                             __ATOMIC_RELAXED, __HIP_MEMORY_SCOPE_AGENT);
        asm volatile("" :: "v"(oc));
        if (oc == (NBLOCKS / SLOTS) - 1) {              // slot-terminal (32nd arrival)
            __hip_atomic_store(&g_cnt[slot * SPAD], 0u,
                               __ATOMIC_RELAXED, __HIP_MEMORY_SCOPE_AGENT);
            asm volatile("s_waitcnt vmcnt(0)" ::: "memory");
            unsigned ol = __hip_atomic_fetch_add(&g_l2[0], 1u,
                                                 __ATOMIC_RELAXED, __HIP_MEMORY_SCOPE_AGENT);
            asm volatile("" :: "v"(ol));
            if (ol == SLOTS - 1) {                      // 64th slot-terminal: finalizer
                __hip_atomic_store(&g_l2[0], 0u,
                                   __ATOMIC_RELAXED, __HIP_MEMORY_SCOPE_AGENT);
                sfin = 1;
            }
        }
    }
    __syncthreads();

    if (sfin) {
        // All 2048 value-adds are complete (each acked before its count-add;
        // count chain fully drained before we got here). One wave reads the
        // 64 slots at the coherent point, reduces, writes out, and re-zeros.
        float s = 0.0f;
        if (threadIdx.x < SLOTS) {
            s = __hip_atomic_load(&g_acc[threadIdx.x * SPAD],
                                  __ATOMIC_RELAXED, __HIP_MEMORY_SCOPE_AGENT);
            __hip_atomic_store(&g_acc[threadIdx.x * SPAD], 0.0f,
                               __ATOMIC_RELAXED, __HIP_MEMORY_SCOPE_AGENT);
        }
        if (threadIdx.x < 64) {
            for (int off = 32; off > 0; off >>= 1)
                s += __shfl_down(s, off, 64);
            if (threadIdx.x == 0)
                out[0] = s * (1.0f / (float)(BB * PP));
        }
    }
}

extern "C" void kernel_launch(void* const* d_in, const int* in_sizes, int n_in,
                              void* d_out, int out_size, void* d_ws, size_t ws_size,
                              hipStream_t stream) {
    const float* voxel   = (const float*)d_in[0];
    const float* points  = (const float*)d_in[1];
    const float* closest = (const float*)d_in[2];
    const float* planes  = (const float*)d_in[3];
    float* out = (float*)d_out;

    hipLaunchKernelGGL(sym_plane_fused_kernel, dim3(NBLOCKS), dim3(256), 0, stream,
                       voxel, points, closest, planes, out);
}